// Round 17
// baseline (192.248 us; speedup 1.0000x reference)
//
#include <hip/hip_runtime.h>
#include <cstddef>
#include <cstdint>

typedef __attribute__((ext_vector_type(8))) short s16x8;
typedef __attribute__((ext_vector_type(4))) short s16x4;
typedef __attribute__((ext_vector_type(4))) float f32x4;
typedef __attribute__((ext_vector_type(4))) unsigned u32x4;

#define MFMA(a, b, c) __builtin_amdgcn_mfma_f32_16x16x32_bf16(a, b, c, 0, 0, 0)
#define LOG2E 1.44269504088896f

__device__ __forceinline__ short f2bf(float x) {
    uint32_t u = __float_as_uint(x);
    u = (u + 0x7FFFu + ((u >> 16) & 1u)) >> 16;   // RNE
    return (short)u;
}

__device__ __forceinline__ void gld16(const void* g, void* l) {
    __builtin_amdgcn_global_load_lds(
        (const __attribute__((address_space(1))) unsigned int*)g,
        (__attribute__((address_space(3))) unsigned int*)l, 16, 0, 0);
}

__device__ __forceinline__ float fexp2(float x) {
#if __has_builtin(__builtin_amdgcn_exp2f)
    return __builtin_amdgcn_exp2f(x);
#else
    return exp2f(x);
#endif
}

__device__ __forceinline__ float frcp(float x) {
#if __has_builtin(__builtin_amdgcn_rcpf)
    return __builtin_amdgcn_rcpf(x);
#else
    return 1.f / x;
#endif
}

__device__ __forceinline__ unsigned cvtpk(float lo, float hi) {
    unsigned r;
    asm("v_cvt_pk_bf16_f32 %0, %1, %2" : "=v"(r) : "v"(lo), "v"(hi));
    return r;
}

// ---------------------------------------------------------------------------
// All 5 weight transposes in one launch. W [K,N=1024] fp32 -> Wt [N,K] bf16.
// ---------------------------------------------------------------------------
struct WtP { const float* W[5]; short* Wt[5]; int K[5]; };

__global__ __launch_bounds__(256)
void conv_wt_b(WtP p) {
    __shared__ float T[64][65];
    const int z = blockIdx.z;
    const int K = p.K[z];
    const int k0 = blockIdx.y << 6, n0 = blockIdx.x << 6;
    if (k0 >= K) return;
    const float* W = p.W[z];
    short* Wt = p.Wt[z];
    const int tr = threadIdx.x >> 4, tc4 = (threadIdx.x & 15) << 2;
    #pragma unroll
    for (int i = 0; i < 4; ++i) {
        const int r = tr + i * 16;
        const float4 v = *(const float4*)(W + (size_t)(k0 + r) * 1024 + n0 + tc4);
        T[r][tc4 + 0] = v.x; T[r][tc4 + 1] = v.y;
        T[r][tc4 + 2] = v.z; T[r][tc4 + 3] = v.w;
    }
    __syncthreads();
    #pragma unroll
    for (int i = 0; i < 4; ++i) {
        const int nr = tr + i * 16;
        s16x4 o;
        o[0] = f2bf(T[tc4 + 0][nr]); o[1] = f2bf(T[tc4 + 1][nr]);
        o[2] = f2bf(T[tc4 + 2][nr]); o[3] = f2bf(T[tc4 + 3][nr]);
        *(s16x4*)(Wt + (size_t)(n0 + nr) * K + k0 + tc4) = o;
    }
}

struct Proj5P {
    const float* Af[5];                 // fp32 A
    const short* A[5];                  // bf16 A
    const short* Bt[5]; const float* bias[5];
    void* Y[5]; int Kd[5]; float alpha[5]; int mode[5];
};

// ---------------------------------------------------------------------------
// proj_gemm128f: 128x128 GEMM, fp32 A fused conversion, BK=32, 32 KiB LDS
// -> 4 blocks/CU (grid 1024 = all blocks resident, single generation).
// Split-wait ledger per tile t:
//   ISSUE_B(t+1) [2 gld16] ; 8 ds_read frags ; 16 MFMA (setprio) ;
//   A_WRITE(t+1) [implicit vmcnt(2): av issued a full tile ago -> covered] ;
//   ISSUE_A(t+2) [4 float4] ; vmcnt(4) retires exactly B(t+1) (A stays in
//   flight across the barrier) ; lgkmcnt(0) ; s_barrier. Tail peels vmcnt(0).
// Swizzle chunk ^= ((row>>1)&3) applied on SOURCE (A reg path + B gld source)
// and on the LDS READ (rule 21): linear LDS, involution consistent.
// modes: 0 = bf16 [M,1024]; 2 = bf16 vt[b,h,d,l] via 2-pass LDS transpose.
// ---------------------------------------------------------------------------
__global__ __launch_bounds__(256, 4)
void proj_gemm128f(Proj5P p) {
    __shared__ __align__(16) short lds[2 * 8192];   // 32 KiB: [buf][A 4096 | B 4096]

    const int tid = threadIdx.x;
    const int w = tid >> 6, lane = tid & 63;
    const int la = lane & 15, kg = lane >> 4;
    const int wr = w >> 1, wc = w & 1;

    const int orig = blockIdx.x;
    const int swz = (orig & 7) * 128 + (orig >> 3);   // cpx = 1024/8
    const int z = swz >> 8;
    const int rem = swz & 255;
    const int bm = rem >> 3, bn = rem & 7;

    const int K = p.Kd[z];
    const int NT = K >> 5;                            // BK=32: 32 or 16 tiles

    // ---- A reg-staging mapping: thread t -> row arow (0..127), k-half ah ----
    const int arow = tid >> 1, ah = tid & 1;
    const int xa = (arow >> 1) & 3;                   // row swizzle key
    const float* gAf = p.Af[z] + (size_t)(bm * 128 + arow) * K;
    // per k-half: bf16 chunks c = 2*ah, 2*ah+1; source elems at (c^xa)*8
    const int ac0 = (2 * ah) ^ xa, ac1 = (2 * ah + 1) ^ xa;
    short* dstA = &lds[arow * 32 + ah * 16];          // linear dest (2 chunks)

    // ---- B gld16 mapping: wave w rows [w*32, w*32+32), 2 loads/thread ----
    const int br0 = w * 32 + (lane >> 2);             // load 0 row
    const int bcc = lane & 3;
    const int xb0 = (br0 >> 1) & 3, xb1 = ((br0 + 16) >> 1) & 3;
    const short* gB0 = p.Bt[z] + (size_t)(bn * 128 + br0) * K + ((bcc ^ xb0) * 8);
    const short* gB1 = p.Bt[z] + (size_t)(bn * 128 + br0 + 16) * K + ((bcc ^ xb1) * 8);
    short* dstB0 = &lds[4096 + w * 1024 + lane * 8];  // wave-base + lane*16B
    short* dstB1 = dstB0 + 512;

    float4 av[2][2];

#define ISSUE_A(t) do {                                                    \
        const size_t ko_ = (size_t)((t) << 5);                             \
        av[0][0] = *(const float4*)(gAf + ko_ + ac0 * 8);                  \
        av[0][1] = *(const float4*)(gAf + ko_ + ac0 * 8 + 4);              \
        av[1][0] = *(const float4*)(gAf + ko_ + ac1 * 8);                  \
        av[1][1] = *(const float4*)(gAf + ko_ + ac1 * 8 + 4);              \
    } while (0)
#define ISSUE_B(t, nb) do {                                                \
        const size_t ko_ = (size_t)((t) << 5);                             \
        gld16(gB0 + ko_, dstB0 + (nb) * 8192);                             \
        gld16(gB1 + ko_, dstB1 + (nb) * 8192);                             \
    } while (0)
#define A_WRITE(nb) do {                                                   \
        u32x4 pk0, pk1;                                                    \
        pk0[0] = cvtpk(av[0][0].x, av[0][0].y);                            \
        pk0[1] = cvtpk(av[0][0].z, av[0][0].w);                            \
        pk0[2] = cvtpk(av[0][1].x, av[0][1].y);                            \
        pk0[3] = cvtpk(av[0][1].z, av[0][1].w);                            \
        pk1[0] = cvtpk(av[1][0].x, av[1][0].y);                            \
        pk1[1] = cvtpk(av[1][0].z, av[1][0].w);                            \
        pk1[2] = cvtpk(av[1][1].x, av[1][1].y);                            \
        pk1[3] = cvtpk(av[1][1].z, av[1][1].w);                            \
        *(u32x4*)(dstA + (nb) * 8192)     = pk0;                           \
        *(u32x4*)(dstA + (nb) * 8192 + 8) = pk1;                           \
    } while (0)

    f32x4 acc[4][4] = {};

    // prologue: A(0), B(0); write A(0) [waits vmcnt(2)]; A(1); retire B(0)
    ISSUE_A(0);
    ISSUE_B(0, 0);
    A_WRITE(0);
    ISSUE_A(1);
    asm volatile("s_waitcnt vmcnt(4)" ::: "memory");   // retires B(0)
    asm volatile("s_waitcnt lgkmcnt(0)" ::: "memory");
    asm volatile("s_barrier" ::: "memory");

    for (int t = 0; t < NT; ++t) {
        const int cb = (t & 1) * 8192;
        const int nbi = (t & 1) ^ 1;
        if (t + 1 < NT) ISSUE_B(t + 1, nbi);
        s16x8 af[4], bf[4];
        #pragma unroll
        for (int m = 0; m < 4; ++m) {
            const int row = wr * 64 + m * 16 + la;
            af[m] = *(const s16x8*)&lds[cb + row * 32 + (kg ^ ((row >> 1) & 3)) * 8];
        }
        #pragma unroll
        for (int n = 0; n < 4; ++n) {
            const int row = wc * 64 + n * 16 + la;
            bf[n] = *(const s16x8*)&lds[cb + 4096 + row * 32 + (kg ^ ((row >> 1) & 3)) * 8];
        }
        __builtin_amdgcn_s_setprio(1);
        #pragma unroll
        for (int m = 0; m < 4; ++m)
            #pragma unroll
            for (int n = 0; n < 4; ++n)
                acc[m][n] = MFMA(af[m], bf[n], acc[m][n]);
        __builtin_amdgcn_s_setprio(0);
        if (t + 1 < NT) {
            A_WRITE(nbi);                              // implicit vmcnt(2): av ready
            if (t + 2 < NT) {
                ISSUE_A(t + 2);                        // out: B(t+1)2 + A(t+2)4
                asm volatile("s_waitcnt vmcnt(4)" ::: "memory");   // B landed
            } else {
                asm volatile("s_waitcnt vmcnt(0)" ::: "memory");
            }
            asm volatile("s_waitcnt lgkmcnt(0)" ::: "memory");
            asm volatile("s_barrier" ::: "memory");
        }
    }
#undef ISSUE_A
#undef ISSUE_B
#undef A_WRITE

    // ---- epilogue ----
    const float* __restrict__ bias = p.bias[z];
    const float alpha = p.alpha[z];
    const int mode = p.mode[z];

    if (mode == 2) {
        // vt[b,h,d,l] via 2-pass 64-row LDS transpose (Tv [64][132] = 16.9 KB)
        short* __restrict__ Y = (short*)p.Y[z];
        short* Tv = lds;
        const int bb_ = (bm * 128) >> 10;
        const int l0g = (bm * 128) & 1023;
        #pragma unroll
        for (int ph = 0; ph < 2; ++ph) {
            asm volatile("s_waitcnt lgkmcnt(0)" ::: "memory");
            asm volatile("s_barrier" ::: "memory");
            if (wc == ph) {
                #pragma unroll
                for (int ni = 0; ni < 4; ++ni) {
                    const int loc = ni * 16 + la;              // 0..63
                    const float bs = bias[bn * 128 + ph * 64 + loc];
                    #pragma unroll
                    for (int mi = 0; mi < 4; ++mi) {
                        const int l0 = wr * 64 + mi * 16 + kg * 4;
                        const unsigned d0 = cvtpk(alpha * (acc[mi][ni][0] + bs),
                                                  alpha * (acc[mi][ni][1] + bs));
                        const unsigned d1 = cvtpk(alpha * (acc[mi][ni][2] + bs),
                                                  alpha * (acc[mi][ni][3] + bs));
                        *(unsigned*)&Tv[loc * 132 + l0]     = d0;
                        *(unsigned*)&Tv[loc * 132 + l0 + 2] = d1;
                    }
                }
            }
            asm volatile("s_waitcnt lgkmcnt(0)" ::: "memory");
            asm volatile("s_barrier" ::: "memory");
            const int hh = bn * 2 + ph;
            #pragma unroll
            for (int s = 0; s < 4; ++s) {
                const int c = tid + (s << 8);                  // 0..1023
                const int loc = c >> 4, seg = c & 15;
                const s16x8 vv = *(const s16x8*)&Tv[loc * 132 + seg * 8];
                *(s16x8*)&Y[((((size_t)bb_ * 16 + hh) * 64 + loc) << 10) + l0g + seg * 8] = vv;
            }
        }
        return;
    }

    #pragma unroll
    for (int n = 0; n < 4; ++n) {
        const int col = bn * 128 + wc * 64 + n * 16 + la;
        const float bs = bias[col];
        #pragma unroll
        for (int m = 0; m < 4; ++m) {
            const int row0 = bm * 128 + wr * 64 + m * 16 + kg * 4;
            #pragma unroll
            for (int r = 0; r < 4; ++r) {
                const float v = alpha * (acc[m][n][r] + bs);
                ((short*)p.Y[z])[(size_t)(row0 + r) * 1024 + col] = f2bf(v);
            }
        }
    }
}

// ---------------------------------------------------------------------------
// proj_gemmO: output projection, 128x64 tile, bf16 A (ctx) via global_load_lds,
// 48 KiB LDS (2 buffers), grid 512 -> 2+ blocks/CU. fp32 output.
// ---------------------------------------------------------------------------
__global__ __launch_bounds__(256, 3)
void proj_gemmO(Proj5P p) {
    __shared__ __align__(16) short lds[2 * 12288];   // 48 KiB

    const int tid = threadIdx.x;
    const int w = tid >> 6, lane = tid & 63;
    const int la = lane & 15, kg = lane >> 4;
    const int wr = w >> 1, wc = w & 1;

    const int orig = blockIdx.x;
    const int swz = (orig & 7) * 64 + (orig >> 3);    // cpx = 512/8
    const int bm = swz >> 4, bn = swz & 15;

    const int K = 1024, NT = 16;

    const int srow = tid >> 3;                        // 0..31
    const int csrc = (tid & 7) ^ (srow & 7);
    const short* gA = p.A[4]  + (size_t)(bm * 128 + srow) * K + csrc * 8;
    const short* gB = p.Bt[4] + (size_t)(bn * 64 + srow) * K + csrc * 8;
    short* dstA = &lds[srow * 64 + (tid & 7) * 8];
    short* dstB = dstA + 8192;

#define STAGE(t, nb) do {                                                  \
        const size_t ko_ = (size_t)((t) << 6);                             \
        _Pragma("unroll")                                                  \
        for (int i = 0; i < 4; ++i)                                        \
            gld16(gA + (size_t)(32 * i) * K + ko_,                         \
                  dstA + (nb) * 12288 + i * 2048);                         \
        _Pragma("unroll")                                                  \
        for (int i = 0; i < 2; ++i)                                        \
            gld16(gB + (size_t)(32 * i) * K + ko_,                         \
                  dstB + (nb) * 12288 + i * 2048);                         \
    } while (0)

    const int c0 = kg ^ (la & 7), c1 = (4 + kg) ^ (la & 7);
    const int aRd = (wr * 64 + la) * 64;
    const int bRd = 8192 + (wc * 32 + la) * 64;

    f32x4 acc[4][2] = {};

    STAGE(0, 0);
    asm volatile("s_waitcnt vmcnt(0)" ::: "memory");
    asm volatile("s_barrier" ::: "memory");

    for (int t = 0; t < NT; ++t) {
        const int cb = (t & 1) * 12288;
        if (t + 1 < NT) STAGE(t + 1, (t & 1) ^ 1);
        s16x8 af[4][2], bf[2][2];
        #pragma unroll
        for (int m = 0; m < 4; ++m) {
            af[m][0] = *(const s16x8*)&lds[cb + aRd + m * 1024 + c0 * 8];
            af[m][1] = *(const s16x8*)&lds[cb + aRd + m * 1024 + c1 * 8];
        }
        #pragma unroll
        for (int n = 0; n < 2; ++n) {
            bf[n][0] = *(const s16x8*)&lds[cb + bRd + n * 1024 + c0 * 8];
            bf[n][1] = *(const s16x8*)&lds[cb + bRd + n * 1024 + c1 * 8];
        }
        __builtin_amdgcn_s_setprio(1);
        #pragma unroll
        for (int m = 0; m < 4; ++m)
            #pragma unroll
            for (int n = 0; n < 2; ++n) {
                acc[m][n] = MFMA(af[m][0], bf[n][0], acc[m][n]);
                acc[m][n] = MFMA(af[m][1], bf[n][1], acc[m][n]);
            }
        __builtin_amdgcn_s_setprio(0);
        if (t + 1 < NT) {
            asm volatile("s_waitcnt vmcnt(0)" ::: "memory");
            asm volatile("s_barrier" ::: "memory");
        }
    }
#undef STAGE

    const float* __restrict__ bias = p.bias[4];
    float* __restrict__ Y = (float*)p.Y[4];
    #pragma unroll
    for (int n = 0; n < 2; ++n) {
        const int col = bn * 64 + wc * 32 + n * 16 + la;
        const float bs = bias[col];
        #pragma unroll
        for (int m = 0; m < 4; ++m) {
            const int row0 = bm * 128 + wr * 64 + m * 16 + kg * 4;
            #pragma unroll
            for (int r = 0; r < 4; ++r)
                Y[(size_t)(row0 + r) * 1024 + col] = acc[m][n][r] + bs;
        }
    }
}

// ---------------------------------------------------------------------------
// Fused gated attention (R6-exact, proven): QBLK=128 (8 waves), KVBLK=64,
// double-buffered K/G/V LDS (66 KB -> 2 blocks/CU), single vmcnt(0)+barrier
// per tile, XCD-grouped decode, max-free exp2 softmax.
// ---------------------------------------------------------------------------
__global__ __launch_bounds__(512)
void attn_mfma(const short* __restrict__ qh, const short* __restrict__ kh,
               const short* __restrict__ gh, const short* __restrict__ vt,
               short* __restrict__ ctx) {
    __shared__ __align__(16) short lds[33792];

    const int tid = threadIdx.x, w = tid >> 6, lane = tid & 63;
    const int la = lane & 15, kg = lane >> 4;

    const int orig = blockIdx.x;
    const int xcd = orig & 7, i = orig >> 3;        // i = 0..63
    const int bh = xcd * 8 + (i >> 3);              // 0..63 (= b*16+h)
    const int qt = i & 7;
    const int b = bh >> 4, h = bh & 15;
    const int q0 = qt << 7;

    const size_t hb = ((size_t)b << 20) + ((size_t)h << 6);
    const size_t vtbase = ((size_t)bh) << 16;

    const int qrow = q0 + w * 16 + la;
    const s16x8 aq0 = *(const s16x8*)(qh + hb + (size_t)qrow * 1024 + kg * 8);
    const s16x8 aq1 = *(const s16x8*)(qh + hb + (size_t)qrow * 1024 + 32 + kg * 8);

    const int sr = tid >> 3, sc = tid & 7;
    const int cs = sc ^ (sr & 7);
    const short* ksrc = kh + hb + (size_t)sr * 1024 + cs * 8;
    const short* gsrc = gh + hb + (size_t)sr * 1024 + cs * 8;
    const short* vsrc = vt + vtbase + (size_t)sr * 1024 + cs * 8;
    const int sdst = tid * 8;

    const int ch0 = (kg ^ (la & 7)) * 8;
    const int ch1 = ((4 + kg) ^ (la & 7)) * 8;
    const int pbase = 24576 + w * 1152;

    float s_run = 0.f;
    f32x4 o[4] = {};

#define ASTG(kt, bb) do {                                                  \
        const size_t kr_ = (size_t)((kt) << 6) * 1024;                     \
        gld16(ksrc + kr_, &lds[(bb) * 4096 + sdst]);                       \
        gld16(gsrc + kr_, &lds[8192 + (bb) * 4096 + sdst]);                \
        gld16(vsrc + ((kt) << 6), &lds[16384 + (bb) * 4096 + sdst]);       \
    } while (0)

    ASTG(0, 0);
    asm volatile("s_waitcnt vmcnt(0)" ::: "memory");
    asm volatile("s_barrier" ::: "memory");

    for (int kt = 0; kt < 16; ++kt) {
        const int cb = (kt & 1) * 4096;
        if (kt < 15) ASTG(kt + 1, (kt + 1) & 1);

        f32x4 st[4] = {}, gt[4] = {};
        #pragma unroll
        for (int nf = 0; nf < 4; ++nf) {
            const int rb = cb + (nf * 16 + la) * 64;
            const s16x8 kb0 = *(const s16x8*)&lds[rb + ch0];
            const s16x8 kb1 = *(const s16x8*)&lds[rb + ch1];
            st[nf] = MFMA(kb0, aq0, st[nf]);
            st[nf] = MFMA(kb1, aq1, st[nf]);
            const s16x8 gb0 = *(const s16x8*)&lds[8192 + rb + ch0];
            const s16x8 gb1 = *(const s16x8*)&lds[8192 + rb + ch1];
            gt[nf] = MFMA(gb0, aq0, gt[nf]);
            gt[nf] = MFMA(gb1, aq1, gt[nf]);
        }

        float ps = 0.f;
        unsigned pkw[4][2];
        #pragma unroll
        for (int nf = 0; nf < 4; ++nf) {
            const float p0 = fexp2(st[nf][0]);
            const float p1 = fexp2(st[nf][1]);
            const float p2 = fexp2(st[nf][2]);
            const float p3 = fexp2(st[nf][3]);
            ps += (p0 + p1) + (p2 + p3);
            const float g0 = frcp(1.f + fexp2(-gt[nf][0]));
            const float g1 = frcp(1.f + fexp2(-gt[nf][1]));
            const float g2 = frcp(1.f + fexp2(-gt[nf][2]));
            const float g3 = frcp(1.f + fexp2(-gt[nf][3]));
            pkw[nf][0] = cvtpk(p0 * g0, p1 * g1);
            pkw[nf][1] = cvtpk(p2 * g2, p3 * g3);
        }
        s_run += ps;

        #pragma unroll
        for (int nf = 0; nf < 4; ++nf) {
            *(unsigned*)&lds[pbase + la * 72 + nf * 16 + kg * 4]     = pkw[nf][0];
            *(unsigned*)&lds[pbase + la * 72 + nf * 16 + kg * 4 + 2] = pkw[nf][1];
        }

        const s16x8 pa0 = *(const s16x8*)&lds[pbase + la * 72 + kg * 8];
        const s16x8 pa1 = *(const s16x8*)&lds[pbase + la * 72 + 32 + kg * 8];
        #pragma unroll
        for (int nf = 0; nf < 4; ++nf) {
            const int rb = cb + (nf * 16 + la) * 64;
            const s16x8 vb0 = *(const s16x8*)&lds[16384 + rb + ch0];
            const s16x8 vb1 = *(const s16x8*)&lds[16384 + rb + ch1];
            o[nf] = MFMA(vb0, pa0, o[nf]);
            o[nf] = MFMA(vb1, pa1, o[nf]);
        }

        if (kt < 15) {
            asm volatile("s_waitcnt vmcnt(0)" ::: "memory");
            asm volatile("s_barrier" ::: "memory");
        }
    }
#undef ASTG

    float sv = s_run;
    sv += __shfl_xor(sv, 16);
    sv += __shfl_xor(sv, 32);
    const float inv = frcp(sv);
    short* crow = ctx + ((size_t)(b * 1024 + qrow) << 10) + (h << 6);
    #pragma unroll
    for (int nf = 0; nf < 4; ++nf) {
        *(unsigned*)(crow + nf * 16 + kg * 4)     = cvtpk(o[nf][0] * inv, o[nf][1] * inv);
        *(unsigned*)(crow + nf * 16 + kg * 4 + 2) = cvtpk(o[nf][2] * inv, o[nf][3] * inv);
    }
}

// ---------------------------------------------------------------------------
extern "C" void kernel_launch(void* const* d_in, const int* in_sizes, int n_in,
                              void* d_out, int out_size, void* d_ws, size_t ws_size,
                              hipStream_t stream) {
    (void)in_sizes; (void)n_in; (void)out_size; (void)ws_size;

    const float* k  = (const float*)d_in[0];
    const float* v  = (const float*)d_in[1];
    const float* q  = (const float*)d_in[2];
    const float* bg = (const float*)d_in[3];
    const float* Wk = (const float*)d_in[4];  const float* bk = (const float*)d_in[5];
    const float* Wv = (const float*)d_in[6];  const float* bv = (const float*)d_in[7];
    const float* Wq = (const float*)d_in[8];  const float* bq = (const float*)d_in[9];
    const float* Wb = (const float*)d_in[10]; const float* bb = (const float*)d_in[11];
    const float* Wo = (const float*)d_in[12]; const float* bo = (const float*)d_in[13];

    short* ws = (short*)d_ws;
    const size_t MN = (size_t)4096 * 1024;
    short* khb  = ws;
    short* qhb  = ws + MN;
    short* ghb  = ws + 2 * MN;
    short* vtb  = ws + 3 * MN;
    short* ctxb = ws + 4 * MN;
    short* wkt  = ws + 5 * MN;
    short* wvt  = wkt + 1048576;
    short* wqt  = wvt + 1048576;
    short* wot  = wqt + 1048576;
    short* wbt  = wot + 1048576;   // 512*1024

    const dim3 blk(256);

    WtP wp;
    wp.W[0] = Wk; wp.Wt[0] = wkt; wp.K[0] = 1024;
    wp.W[1] = Wv; wp.Wt[1] = wvt; wp.K[1] = 1024;
    wp.W[2] = Wq; wp.Wt[2] = wqt; wp.K[2] = 1024;
    wp.W[3] = Wb; wp.Wt[3] = wbt; wp.K[3] = 512;
    wp.W[4] = Wo; wp.Wt[4] = wot; wp.K[4] = 1024;
    conv_wt_b<<<dim3(16, 16, 5), blk, 0, stream>>>(wp);

    Proj5P p5;
    p5.Af[0] = k;  p5.A[0] = nullptr; p5.Bt[0] = wkt; p5.bias[0] = bk;
    p5.Y[0] = khb; p5.Kd[0] = 1024; p5.alpha[0] = LOG2E;  p5.mode[0] = 0;   // exp2 domain
    p5.Af[1] = q;  p5.A[1] = nullptr; p5.Bt[1] = wqt; p5.bias[1] = bq;
    p5.Y[1] = qhb; p5.Kd[1] = 1024; p5.alpha[1] = 0.125f; p5.mode[1] = 0;   // 1/sqrt(64)
    p5.Af[2] = bg; p5.A[2] = nullptr; p5.Bt[2] = wbt; p5.bias[2] = bb;
    p5.Y[2] = ghb; p5.Kd[2] = 512;  p5.alpha[2] = LOG2E;  p5.mode[2] = 0;   // exp2 domain
    p5.Af[3] = v;  p5.A[3] = nullptr; p5.Bt[3] = wvt; p5.bias[3] = bv;
    p5.Y[3] = vtb; p5.Kd[3] = 1024; p5.alpha[3] = 1.0f;   p5.mode[3] = 2;   // per-head T
    p5.Af[4] = nullptr; p5.A[4] = ctxb; p5.Bt[4] = wot; p5.bias[4] = bo;
    p5.Y[4] = d_out; p5.Kd[4] = 1024; p5.alpha[4] = 1.0f; p5.mode[4] = 1;   // fp32 out

    proj_gemm128f<<<dim3(1024), blk, 0, stream>>>(p5);         // z = 0..3, fp32 A
    attn_mfma<<<dim3(512), dim3(512), 0, stream>>>(qhb, khb, ghb, vtb, ctxb);
    proj_gemmO<<<dim3(512), blk, 0, stream>>>(p5);             // z = 4, 128x64
}

// Round 18
// 106.520 us; speedup vs baseline: 1.8048x; 1.8048x over previous
//
#include <hip/hip_runtime.h>
#include <cstddef>
#include <cstdint>

typedef __attribute__((ext_vector_type(8))) short s16x8;
typedef __attribute__((ext_vector_type(4))) short s16x4;
typedef __attribute__((ext_vector_type(4))) float f32x4;
typedef __attribute__((ext_vector_type(4))) unsigned u32x4;

#define MFMA(a, b, c) __builtin_amdgcn_mfma_f32_16x16x32_bf16(a, b, c, 0, 0, 0)
#define LOG2E 1.44269504088896f

__device__ __forceinline__ short f2bf(float x) {
    uint32_t u = __float_as_uint(x);
    u = (u + 0x7FFFu + ((u >> 16) & 1u)) >> 16;   // RNE
    return (short)u;
}

__device__ __forceinline__ void gld16(const void* g, void* l) {
    __builtin_amdgcn_global_load_lds(
        (const __attribute__((address_space(1))) unsigned int*)g,
        (__attribute__((address_space(3))) unsigned int*)l, 16, 0, 0);
}

__device__ __forceinline__ float fexp2(float x) {
#if __has_builtin(__builtin_amdgcn_exp2f)
    return __builtin_amdgcn_exp2f(x);
#else
    return exp2f(x);
#endif
}

__device__ __forceinline__ float frcp(float x) {
#if __has_builtin(__builtin_amdgcn_rcpf)
    return __builtin_amdgcn_rcpf(x);
#else
    return 1.f / x;
#endif
}

__device__ __forceinline__ unsigned cvtpk(float lo, float hi) {
    unsigned r;
    asm("v_cvt_pk_bf16_f32 %0, %1, %2" : "=v"(r) : "v"(lo), "v"(hi));
    return r;
}

// ---------------------------------------------------------------------------
// All 5 weight transposes in one launch. W [K,N=1024] fp32 -> Wt [N,K] bf16.
// ---------------------------------------------------------------------------
struct WtP { const float* W[5]; short* Wt[5]; int K[5]; };

__global__ __launch_bounds__(256)
void conv_wt_b(WtP p) {
    __shared__ float T[64][65];
    const int z = blockIdx.z;
    const int K = p.K[z];
    const int k0 = blockIdx.y << 6, n0 = blockIdx.x << 6;
    if (k0 >= K) return;
    const float* W = p.W[z];
    short* Wt = p.Wt[z];
    const int tr = threadIdx.x >> 4, tc4 = (threadIdx.x & 15) << 2;
    #pragma unroll
    for (int i = 0; i < 4; ++i) {
        const int r = tr + i * 16;
        const float4 v = *(const float4*)(W + (size_t)(k0 + r) * 1024 + n0 + tc4);
        T[r][tc4 + 0] = v.x; T[r][tc4 + 1] = v.y;
        T[r][tc4 + 2] = v.z; T[r][tc4 + 3] = v.w;
    }
    __syncthreads();
    #pragma unroll
    for (int i = 0; i < 4; ++i) {
        const int nr = tr + i * 16;
        s16x4 o;
        o[0] = f2bf(T[tc4 + 0][nr]); o[1] = f2bf(T[tc4 + 1][nr]);
        o[2] = f2bf(T[tc4 + 2][nr]); o[3] = f2bf(T[tc4 + 3][nr]);
        *(s16x4*)(Wt + (size_t)(n0 + nr) * K + k0 + tc4) = o;
    }
}

struct Proj5P {
    const float* Af[5];                 // fp32 A
    const short* A[5];                  // bf16 A
    const short* Bt[5]; const float* bias[5];
    void* Y[5]; int Kd[5]; float alpha[5]; int mode[5];
};

// ---------------------------------------------------------------------------
// proj_gemm128f: 128x128 dbuf GEMM, fp32 A (split-wait reg-staging).
// R10/R15-exact — measured best net (proj4 ~66.5us fused, no conv_all).
//   Per tile t: ISSUE_B(t+1) at top; frags+MFMA; A_WRITE (compiler waits only
//   the 8 A loads, vmcnt~4, B still in flight); ISSUE_A(t+2); vmcnt(8)
//   [retires exactly B(t+1)]; lgkmcnt(0); barrier. Tail peels vmcnt(0).
// z = 0..3 (k,q,bg,v projections), grid 1024, 2 blocks/CU.
// ---------------------------------------------------------------------------
__global__ __launch_bounds__(256, 2)
void proj_gemm128f(Proj5P p) {
    __shared__ __align__(16) short lds[2 * 16384];   // 64 KiB

    const int tid = threadIdx.x;
    const int w = tid >> 6, lane = tid & 63;
    const int la = lane & 15, kg = lane >> 4;
    const int wr = w >> 1, wc = w & 1;

    const int orig = blockIdx.x;
    const int swz = (orig & 7) * 128 + (orig >> 3);   // cpx = 1024/8
    const int z = swz >> 8;
    const int rem = swz & 255;
    const int bm = rem >> 3, bn = rem & 7;

    const int K = p.Kd[z];
    const int NT = K >> 6;

    const int srow = tid >> 3;                        // 0..31 (+32i slices)
    const int csrc = (tid & 7) ^ (srow & 7);          // inverse swizzle
    const float* gAf = p.Af[z] + (size_t)(bm * 128 + srow) * K + csrc * 8;
    const short* gB  = p.Bt[z] + (size_t)(bn * 128 + srow) * K + csrc * 8;
    short* dstA = &lds[srow * 64 + (tid & 7) * 8];
    short* dstB = dstA + 8192;

    float4 av[4][2];

#define ISSUE_A(t) do {                                                    \
        const size_t ko_ = (size_t)((t) << 6);                             \
        _Pragma("unroll")                                                  \
        for (int i = 0; i < 4; ++i) {                                      \
            av[i][0] = *(const float4*)(gAf + (size_t)(32 * i) * K + ko_);     \
            av[i][1] = *(const float4*)(gAf + (size_t)(32 * i) * K + ko_ + 4); \
        }                                                                  \
    } while (0)
#define ISSUE_B(t, nb) do {                                                \
        const size_t ko_ = (size_t)((t) << 6);                             \
        _Pragma("unroll")                                                  \
        for (int i = 0; i < 4; ++i)                                        \
            gld16(gB + (size_t)(32 * i) * K + ko_,                         \
                  dstB + (nb) * 16384 + i * 2048);                         \
    } while (0)
#define A_WRITE(nb) do {                                                   \
        _Pragma("unroll")                                                  \
        for (int i = 0; i < 4; ++i) {                                      \
            u32x4 pk;                                                      \
            pk[0] = cvtpk(av[i][0].x, av[i][0].y);                         \
            pk[1] = cvtpk(av[i][0].z, av[i][0].w);                         \
            pk[2] = cvtpk(av[i][1].x, av[i][1].y);                         \
            pk[3] = cvtpk(av[i][1].z, av[i][1].w);                         \
            *(u32x4*)(dstA + (nb) * 16384 + i * 2048) = pk;                \
        }                                                                  \
    } while (0)

    const int c0 = kg ^ (la & 7), c1 = (4 + kg) ^ (la & 7);
    const int aRd = (wr * 64 + la) * 64;
    const int bRd = 8192 + (wc * 64 + la) * 64;

    f32x4 acc[4][4] = {};

    // prologue
    ISSUE_A(0);
    ISSUE_B(0, 0);
    A_WRITE(0);                                       // compiler waits av only
    asm volatile("s_waitcnt vmcnt(0) lgkmcnt(0)" ::: "memory");
    asm volatile("s_barrier" ::: "memory");
    ISSUE_A(1);                                       // A(1) in flight: 8

    for (int t = 0; t < NT; ++t) {
        const int cb = (t & 1) * 16384;
        const int nbi = (t & 1) ^ 1;
        if (t + 1 < NT) ISSUE_B(t + 1, nbi);          // A(t+1) older, B younger
        s16x8 af[4][2], bf[4][2];
        #pragma unroll
        for (int m = 0; m < 4; ++m) {
            af[m][0] = *(const s16x8*)&lds[cb + aRd + m * 1024 + c0 * 8];
            af[m][1] = *(const s16x8*)&lds[cb + aRd + m * 1024 + c1 * 8];
        }
        #pragma unroll
        for (int n = 0; n < 4; ++n) {
            bf[n][0] = *(const s16x8*)&lds[cb + bRd + n * 1024 + c0 * 8];
            bf[n][1] = *(const s16x8*)&lds[cb + bRd + n * 1024 + c1 * 8];
        }
        __builtin_amdgcn_s_setprio(1);
        #pragma unroll
        for (int m = 0; m < 4; ++m)
            #pragma unroll
            for (int n = 0; n < 4; ++n) {
                acc[m][n] = MFMA(af[m][0], bf[n][0], acc[m][n]);
                acc[m][n] = MFMA(af[m][1], bf[n][1], acc[m][n]);
            }
        __builtin_amdgcn_s_setprio(0);
        if (t + 1 < NT) {
            A_WRITE(nbi);                             // waits av (vmcnt~4)
            if (t + 2 < NT) {
                ISSUE_A(t + 2);                       // out: B(t+1)4 + A(t+2)8
                asm volatile("s_waitcnt vmcnt(8)" ::: "memory");   // B landed
            } else {
                asm volatile("s_waitcnt vmcnt(0)" ::: "memory");
            }
            asm volatile("s_waitcnt lgkmcnt(0)" ::: "memory");
            asm volatile("s_barrier" ::: "memory");
        }
    }
#undef ISSUE_A
#undef ISSUE_B
#undef A_WRITE

    // ---- epilogue ----
    const float* __restrict__ bias = p.bias[z];
    const float alpha = p.alpha[z];
    const int mode = p.mode[z];

    if (mode == 2) {
        short* __restrict__ Y = (short*)p.Y[z];
        short* Tv = lds;                          // [128][132] shorts
        asm volatile("s_waitcnt lgkmcnt(0)" ::: "memory");
        asm volatile("s_barrier" ::: "memory");
        #pragma unroll
        for (int ni = 0; ni < 4; ++ni) {
            const int rrow = wc * 64 + ni * 16 + la;
            const float bs = bias[bn * 128 + rrow];
            #pragma unroll
            for (int mi = 0; mi < 4; ++mi) {
                const int l0 = wr * 64 + mi * 16 + kg * 4;
                const unsigned d0 = cvtpk(alpha * (acc[mi][ni][0] + bs),
                                          alpha * (acc[mi][ni][1] + bs));
                const unsigned d1 = cvtpk(alpha * (acc[mi][ni][2] + bs),
                                          alpha * (acc[mi][ni][3] + bs));
                *(unsigned*)&Tv[rrow * 132 + l0]     = d0;
                *(unsigned*)&Tv[rrow * 132 + l0 + 2] = d1;
            }
        }
        asm volatile("s_waitcnt lgkmcnt(0)" ::: "memory");
        asm volatile("s_barrier" ::: "memory");
        const int bb_ = (bm * 128) >> 10;
        const int l0g = (bm * 128) & 1023;
        #pragma unroll
        for (int s = 0; s < 8; ++s) {
            const int c = tid + (s << 8);
            const int rr = c >> 4, seg = c & 15;
            const int hh = bn * 2 + (rr >> 6), dd = rr & 63;
            const s16x8 vv = *(const s16x8*)&Tv[rr * 132 + seg * 8];
            *(s16x8*)&Y[((((size_t)bb_ * 16 + hh) * 64 + dd) << 10) + l0g + seg * 8] = vv;
        }
        return;
    }

    #pragma unroll
    for (int n = 0; n < 4; ++n) {
        const int col = bn * 128 + wc * 64 + n * 16 + la;
        const float bs = bias[col];
        #pragma unroll
        for (int m = 0; m < 4; ++m) {
            const int row0 = bm * 128 + wr * 64 + m * 16 + kg * 4;
            #pragma unroll
            for (int r = 0; r < 4; ++r) {
                const float v = alpha * (acc[m][n][r] + bs);
                ((short*)p.Y[z])[(size_t)(row0 + r) * 1024 + col] = f2bf(v);
            }
        }
    }
}

// ---------------------------------------------------------------------------
// proj_gemmO: output projection, 128x64 tile, bf16 A (ctx) via global_load_lds,
// 48 KiB LDS (2 buffers), grid 512 -> 2+ blocks/CU. fp32 output.
// ---------------------------------------------------------------------------
__global__ __launch_bounds__(256, 3)
void proj_gemmO(Proj5P p) {
    __shared__ __align__(16) short lds[2 * 12288];   // 48 KiB

    const int tid = threadIdx.x;
    const int w = tid >> 6, lane = tid & 63;
    const int la = lane & 15, kg = lane >> 4;
    const int wr = w >> 1, wc = w & 1;

    const int orig = blockIdx.x;
    const int swz = (orig & 7) * 64 + (orig >> 3);    // cpx = 512/8
    const int bm = swz >> 4, bn = swz & 15;

    const int K = 1024, NT = 16;

    const int srow = tid >> 3;                        // 0..31
    const int csrc = (tid & 7) ^ (srow & 7);
    const short* gA = p.A[4]  + (size_t)(bm * 128 + srow) * K + csrc * 8;
    const short* gB = p.Bt[4] + (size_t)(bn * 64 + srow) * K + csrc * 8;
    short* dstA = &lds[srow * 64 + (tid & 7) * 8];
    short* dstB = dstA + 8192;

#define STAGE(t, nb) do {                                                  \
        const size_t ko_ = (size_t)((t) << 6);                             \
        _Pragma("unroll")                                                  \
        for (int i = 0; i < 4; ++i)                                        \
            gld16(gA + (size_t)(32 * i) * K + ko_,                         \
                  dstA + (nb) * 12288 + i * 2048);                         \
        _Pragma("unroll")                                                  \
        for (int i = 0; i < 2; ++i)                                        \
            gld16(gB + (size_t)(32 * i) * K + ko_,                         \
                  dstB + (nb) * 12288 + i * 2048);                         \
    } while (0)

    const int c0 = kg ^ (la & 7), c1 = (4 + kg) ^ (la & 7);
    const int aRd = (wr * 64 + la) * 64;
    const int bRd = 8192 + (wc * 32 + la) * 64;

    f32x4 acc[4][2] = {};

    STAGE(0, 0);
    asm volatile("s_waitcnt vmcnt(0)" ::: "memory");
    asm volatile("s_barrier" ::: "memory");

    for (int t = 0; t < NT; ++t) {
        const int cb = (t & 1) * 12288;
        if (t + 1 < NT) STAGE(t + 1, (t & 1) ^ 1);
        s16x8 af[4][2], bf[2][2];
        #pragma unroll
        for (int m = 0; m < 4; ++m) {
            af[m][0] = *(const s16x8*)&lds[cb + aRd + m * 1024 + c0 * 8];
            af[m][1] = *(const s16x8*)&lds[cb + aRd + m * 1024 + c1 * 8];
        }
        #pragma unroll
        for (int n = 0; n < 2; ++n) {
            bf[n][0] = *(const s16x8*)&lds[cb + bRd + n * 1024 + c0 * 8];
            bf[n][1] = *(const s16x8*)&lds[cb + bRd + n * 1024 + c1 * 8];
        }
        __builtin_amdgcn_s_setprio(1);
        #pragma unroll
        for (int m = 0; m < 4; ++m)
            #pragma unroll
            for (int n = 0; n < 2; ++n) {
                acc[m][n] = MFMA(af[m][0], bf[n][0], acc[m][n]);
                acc[m][n] = MFMA(af[m][1], bf[n][1], acc[m][n]);
            }
        __builtin_amdgcn_s_setprio(0);
        if (t + 1 < NT) {
            asm volatile("s_waitcnt vmcnt(0)" ::: "memory");
            asm volatile("s_barrier" ::: "memory");
        }
    }
#undef STAGE

    const float* __restrict__ bias = p.bias[4];
    float* __restrict__ Y = (float*)p.Y[4];
    #pragma unroll
    for (int n = 0; n < 2; ++n) {
        const int col = bn * 64 + wc * 32 + n * 16 + la;
        const float bs = bias[col];
        #pragma unroll
        for (int m = 0; m < 4; ++m) {
            const int row0 = bm * 128 + wr * 64 + m * 16 + kg * 4;
            #pragma unroll
            for (int r = 0; r < 4; ++r)
                Y[(size_t)(row0 + r) * 1024 + col] = acc[m][n][r] + bs;
        }
    }
}

// ---------------------------------------------------------------------------
// Fused gated attention (R6-exact, proven): QBLK=128 (8 waves), KVBLK=64,
// double-buffered K/G/V LDS (66 KB -> 2 blocks/CU), single vmcnt(0)+barrier
// per tile, XCD-grouped decode, max-free exp2 softmax.
// ---------------------------------------------------------------------------
__global__ __launch_bounds__(512)
void attn_mfma(const short* __restrict__ qh, const short* __restrict__ kh,
               const short* __restrict__ gh, const short* __restrict__ vt,
               short* __restrict__ ctx) {
    __shared__ __align__(16) short lds[33792];

    const int tid = threadIdx.x, w = tid >> 6, lane = tid & 63;
    const int la = lane & 15, kg = lane >> 4;

    const int orig = blockIdx.x;
    const int xcd = orig & 7, i = orig >> 3;        // i = 0..63
    const int bh = xcd * 8 + (i >> 3);              // 0..63 (= b*16+h)
    const int qt = i & 7;
    const int b = bh >> 4, h = bh & 15;
    const int q0 = qt << 7;

    const size_t hb = ((size_t)b << 20) + ((size_t)h << 6);
    const size_t vtbase = ((size_t)bh) << 16;

    const int qrow = q0 + w * 16 + la;
    const s16x8 aq0 = *(const s16x8*)(qh + hb + (size_t)qrow * 1024 + kg * 8);
    const s16x8 aq1 = *(const s16x8*)(qh + hb + (size_t)qrow * 1024 + 32 + kg * 8);

    const int sr = tid >> 3, sc = tid & 7;
    const int cs = sc ^ (sr & 7);
    const short* ksrc = kh + hb + (size_t)sr * 1024 + cs * 8;
    const short* gsrc = gh + hb + (size_t)sr * 1024 + cs * 8;
    const short* vsrc = vt + vtbase + (size_t)sr * 1024 + cs * 8;
    const int sdst = tid * 8;

    const int ch0 = (kg ^ (la & 7)) * 8;
    const int ch1 = ((4 + kg) ^ (la & 7)) * 8;
    const int pbase = 24576 + w * 1152;

    float s_run = 0.f;
    f32x4 o[4] = {};

#define ASTG(kt, bb) do {                                                  \
        const size_t kr_ = (size_t)((kt) << 6) * 1024;                     \
        gld16(ksrc + kr_, &lds[(bb) * 4096 + sdst]);                       \
        gld16(gsrc + kr_, &lds[8192 + (bb) * 4096 + sdst]);                \
        gld16(vsrc + ((kt) << 6), &lds[16384 + (bb) * 4096 + sdst]);       \
    } while (0)

    ASTG(0, 0);
    asm volatile("s_waitcnt vmcnt(0)" ::: "memory");
    asm volatile("s_barrier" ::: "memory");

    for (int kt = 0; kt < 16; ++kt) {
        const int cb = (kt & 1) * 4096;
        if (kt < 15) ASTG(kt + 1, (kt + 1) & 1);

        f32x4 st[4] = {}, gt[4] = {};
        #pragma unroll
        for (int nf = 0; nf < 4; ++nf) {
            const int rb = cb + (nf * 16 + la) * 64;
            const s16x8 kb0 = *(const s16x8*)&lds[rb + ch0];
            const s16x8 kb1 = *(const s16x8*)&lds[rb + ch1];
            st[nf] = MFMA(kb0, aq0, st[nf]);
            st[nf] = MFMA(kb1, aq1, st[nf]);
            const s16x8 gb0 = *(const s16x8*)&lds[8192 + rb + ch0];
            const s16x8 gb1 = *(const s16x8*)&lds[8192 + rb + ch1];
            gt[nf] = MFMA(gb0, aq0, gt[nf]);
            gt[nf] = MFMA(gb1, aq1, gt[nf]);
        }

        float ps = 0.f;
        unsigned pkw[4][2];
        #pragma unroll
        for (int nf = 0; nf < 4; ++nf) {
            const float p0 = fexp2(st[nf][0]);
            const float p1 = fexp2(st[nf][1]);
            const float p2 = fexp2(st[nf][2]);
            const float p3 = fexp2(st[nf][3]);
            ps += (p0 + p1) + (p2 + p3);
            const float g0 = frcp(1.f + fexp2(-gt[nf][0]));
            const float g1 = frcp(1.f + fexp2(-gt[nf][1]));
            const float g2 = frcp(1.f + fexp2(-gt[nf][2]));
            const float g3 = frcp(1.f + fexp2(-gt[nf][3]));
            pkw[nf][0] = cvtpk(p0 * g0, p1 * g1);
            pkw[nf][1] = cvtpk(p2 * g2, p3 * g3);
        }
        s_run += ps;

        #pragma unroll
        for (int nf = 0; nf < 4; ++nf) {
            *(unsigned*)&lds[pbase + la * 72 + nf * 16 + kg * 4]     = pkw[nf][0];
            *(unsigned*)&lds[pbase + la * 72 + nf * 16 + kg * 4 + 2] = pkw[nf][1];
        }

        const s16x8 pa0 = *(const s16x8*)&lds[pbase + la * 72 + kg * 8];
        const s16x8 pa1 = *(const s16x8*)&lds[pbase + la * 72 + 32 + kg * 8];
        #pragma unroll
        for (int nf = 0; nf < 4; ++nf) {
            const int rb = cb + (nf * 16 + la) * 64;
            const s16x8 vb0 = *(const s16x8*)&lds[16384 + rb + ch0];
            const s16x8 vb1 = *(const s16x8*)&lds[16384 + rb + ch1];
            o[nf] = MFMA(vb0, pa0, o[nf]);
            o[nf] = MFMA(vb1, pa1, o[nf]);
        }

        if (kt < 15) {
            asm volatile("s_waitcnt vmcnt(0)" ::: "memory");
            asm volatile("s_barrier" ::: "memory");
        }
    }
#undef ASTG

    float sv = s_run;
    sv += __shfl_xor(sv, 16);
    sv += __shfl_xor(sv, 32);
    const float inv = frcp(sv);
    short* crow = ctx + ((size_t)(b * 1024 + qrow) << 10) + (h << 6);
    #pragma unroll
    for (int nf = 0; nf < 4; ++nf) {
        *(unsigned*)(crow + nf * 16 + kg * 4)     = cvtpk(o[nf][0] * inv, o[nf][1] * inv);
        *(unsigned*)(crow + nf * 16 + kg * 4 + 2) = cvtpk(o[nf][2] * inv, o[nf][3] * inv);
    }
}

// ---------------------------------------------------------------------------
extern "C" void kernel_launch(void* const* d_in, const int* in_sizes, int n_in,
                              void* d_out, int out_size, void* d_ws, size_t ws_size,
                              hipStream_t stream) {
    (void)in_sizes; (void)n_in; (void)out_size; (void)ws_size;

    const float* k  = (const float*)d_in[0];
    const float* v  = (const float*)d_in[1];
    const float* q  = (const float*)d_in[2];
    const float* bg = (const float*)d_in[3];
    const float* Wk = (const float*)d_in[4];  const float* bk = (const float*)d_in[5];
    const float* Wv = (const float*)d_in[6];  const float* bv = (const float*)d_in[7];
    const float* Wq = (const float*)d_in[8];  const float* bq = (const float*)d_in[9];
    const float* Wb = (const float*)d_in[10]; const float* bb = (const float*)d_in[11];
    const float* Wo = (const float*)d_in[12]; const float* bo = (const float*)d_in[13];

    short* ws = (short*)d_ws;
    const size_t MN = (size_t)4096 * 1024;
    short* khb  = ws;
    short* qhb  = ws + MN;
    short* ghb  = ws + 2 * MN;
    short* vtb  = ws + 3 * MN;
    short* ctxb = ws + 4 * MN;
    short* wkt  = ws + 5 * MN;
    short* wvt  = wkt + 1048576;
    short* wqt  = wvt + 1048576;
    short* wot  = wqt + 1048576;
    short* wbt  = wot + 1048576;   // 512*1024

    const dim3 blk(256);

    WtP wp;
    wp.W[0] = Wk; wp.Wt[0] = wkt; wp.K[0] = 1024;
    wp.W[1] = Wv; wp.Wt[1] = wvt; wp.K[1] = 1024;
    wp.W[2] = Wq; wp.Wt[2] = wqt; wp.K[2] = 1024;
    wp.W[3] = Wb; wp.Wt[3] = wbt; wp.K[3] = 512;
    wp.W[4] = Wo; wp.Wt[4] = wot; wp.K[4] = 1024;
    conv_wt_b<<<dim3(16, 16, 5), blk, 0, stream>>>(wp);

    Proj5P p5;
    p5.Af[0] = k;  p5.A[0] = nullptr; p5.Bt[0] = wkt; p5.bias[0] = bk;
    p5.Y[0] = khb; p5.Kd[0] = 1024; p5.alpha[0] = LOG2E;  p5.mode[0] = 0;   // exp2 domain
    p5.Af[1] = q;  p5.A[1] = nullptr; p5.Bt[1] = wqt; p5.bias[1] = bq;
    p5.Y[1] = qhb; p5.Kd[1] = 1024; p5.alpha[1] = 0.125f; p5.mode[1] = 0;   // 1/sqrt(64)
    p5.Af[2] = bg; p5.A[2] = nullptr; p5.Bt[2] = wbt; p5.bias[2] = bb;
    p5.Y[2] = ghb; p5.Kd[2] = 512;  p5.alpha[2] = LOG2E;  p5.mode[2] = 0;   // exp2 domain
    p5.Af[3] = v;  p5.A[3] = nullptr; p5.Bt[3] = wvt; p5.bias[3] = bv;
    p5.Y[3] = vtb; p5.Kd[3] = 1024; p5.alpha[3] = 1.0f;   p5.mode[3] = 2;   // per-head T
    p5.Af[4] = nullptr; p5.A[4] = ctxb; p5.Bt[4] = wot; p5.bias[4] = bo;
    p5.Y[4] = d_out; p5.Kd[4] = 1024; p5.alpha[4] = 1.0f; p5.mode[4] = 1;   // fp32 out

    proj_gemm128f<<<dim3(1024), blk, 0, stream>>>(p5);         // z = 0..3, fp32 A
    attn_mfma<<<dim3(512), dim3(512), 0, stream>>>(qhb, khb, ghb, vtb, ctxb);
    proj_gemmO<<<dim3(512), blk, 0, stream>>>(p5);             // z = 4, 128x64
}